// Round 10
// baseline (193.007 us; speedup 1.0000x reference)
//
#include <hip/hip_runtime.h>

#define T_LEN 50
#define I_IN 2
#define HID 4

typedef float f2 __attribute__((ext_vector_type(2)));

__device__ __forceinline__ float EXP2(float x){
#if __has_builtin(__builtin_amdgcn_exp2f)
    return __builtin_amdgcn_exp2f(x);
#else
    return exp2f(x);
#endif
}
__device__ __forceinline__ float RCP(float x){
#if __has_builtin(__builtin_amdgcn_rcpf)
    return __builtin_amdgcn_rcpf(x);
#else
    return 1.0f/x;
#endif
}

__device__ __forceinline__ f2 splat(float v){ f2 r; r.x = v; r.y = v; return r; }

// packed fp32 fma -> v_pk_fma_f32 (worst case scalarizes to 2 v_fma, still fine)
__device__ __forceinline__ f2 pkfma(f2 a, f2 b, f2 c){
#if __has_builtin(__builtin_elementwise_fma)
    return __builtin_elementwise_fma(a, b, c);
#else
    f2 r; r.x = fmaf(a.x,b.x,c.x); r.y = fmaf(a.y,b.y,c.y); return r;
#endif
}
__device__ __forceinline__ f2 pkfma_s(float w, f2 x, f2 c){ return pkfma(splat(w), x, c); }

// Packed polynomial 2^x for both pair elements. Replaces 2 scalar v_exp_f32
// (~16 issue-cyc each) with ~11 mostly-packed FMA-pipe ops (~24 cyc total).
// Split: x = r + f, r=round(x), f in [-0.5,0.5]; 2^f by degree-4 poly
// (rel err ~4e-5); scale by 2^r via hw v_ldexp_f32 (inline asm, no libcall).
__device__ __forceinline__ f2 exp2_pk(f2 x){
    f2 r; r.x = __builtin_rintf(x.x); r.y = __builtin_rintf(x.y);
    const f2 f = x - r;
    f2 p = pkfma(f, splat(0.00961813f), splat(0.0555041f));
    p = pkfma(f, p, splat(0.2402265f));
    p = pkfma(f, p, splat(0.6931472f));
    p = pkfma(f, p, splat(1.0f));
    const int ix = (int)r.x, iy = (int)r.y;
    float ex, ey;
    asm("v_ldexp_f32 %0, %1, %2" : "=v"(ex) : "v"(p.x), "v"(ix));
    asm("v_ldexp_f32 %0, %1, %2" : "=v"(ey) : "v"(p.y), "v"(iy));
    f2 o; o.x = ex; o.y = ey; return o;
}

// quad_perm DPP move. Broadcast lane K of quad: CTRL=K*0x55. Swap pairs: 0xB1.
template<int CTRL>
__device__ __forceinline__ int qdpp_i(int v){
#if __has_builtin(__builtin_amdgcn_mov_dpp)
    return __builtin_amdgcn_mov_dpp(v, CTRL, 0xF, 0xF, true);
#else
    int lane = threadIdx.x & 63;
    int sel = (CTRL >> (2*(lane & 3))) & 3;
    return __shfl(v, (lane & ~3) + sel, 64);
#endif
}
template<int CTRL>
__device__ __forceinline__ float qdpp(float v){
    return __int_as_float(qdpp_i<CTRL>(__float_as_int(v)));
}
template<int CTRL>
__device__ __forceinline__ f2 qdpp2(f2 v){
    f2 r; r.x = qdpp<CTRL>(v.x); r.y = qdpp<CTRL>(v.y); return r;
}

// Packed-pair LSTM pointwise stage (two independent batch elements per lane).
// Gate pre-activations pre-scaled: i,f,o by S1=-log2e; g by S2=-2log2e.
// c' = [c*B*C + (1-q)*A] * rcp(A*B*C)  with p,r,q = 2^{scaled gates}
// h  = (1-u)*rcp((1+s)(1+u)),  s=2^{S1*o}, u=2^{S2*c'}  (clamped, finite-safe)
// exp -> packed poly (FMA pipe); rcp stays hw (r8: rcp offload ~neutral).
__device__ __forceinline__ void lstm_act2(const f2 g[4], f2& c, f2& h){
    const float S2 = -2.8853900817779268f;
    const f2 one = splat(1.0f);
    const f2 p = exp2_pk(g[0]);
    const f2 r = exp2_pk(g[1]);
    const f2 q = exp2_pk(g[2]);
    const f2 s = exp2_pk(g[3]);
    const f2 A  = one + r;
    const f2 BC = (one + p) * (one + q);
    const f2 num = pkfma(c, BC, (one - q) * A);
    const f2 den = A * BC;
    f2 rd; rd.x = RCP(den.x); rd.y = RCP(den.y);
    c = num * rd;
    f2 ua = c * splat(S2);
    ua.x = fminf(ua.x, 96.0f); ua.y = fminf(ua.y, 96.0f);
    const f2 u = exp2_pk(ua);
    const f2 dh = (one + s) * (one + u);
    f2 rh; rh.x = RCP(dh.x); rh.y = RCP(dh.y);
    h = (one - u) * rh;
}

__global__ __launch_bounds__(256) void lstm_fused(
    const float* __restrict__ x,
    const float* __restrict__ Wih0, const float* __restrict__ Whh0,
    const float* __restrict__ bih0, const float* __restrict__ bhh0,
    const float* __restrict__ Wih1, const float* __restrict__ Whh1,
    const float* __restrict__ bih1, const float* __restrict__ bhh1,
    const float* __restrict__ Wout, const float* __restrict__ bout,
    float* __restrict__ out, int B)
{
    __shared__ float wout_s[T_LEN*HID];
    const int tid = threadIdx.x;
    if (tid < T_LEN*HID) wout_s[tid] = Wout[tid];
    __syncthreads();

    const int gtid = blockIdx.x*256 + tid;
    const int q2 = gtid >> 2;          // quad id, owns elements 2*q2, 2*q2+1
    const int j = tid & 3;             // hidden unit owned by this lane
    const int e0 = q2*2;
    if (e0 >= B) return;

    const float S1 = -1.4426950408889634f;   // -log2(e)
    const float S2 = -2.8853900817779268f;   // -2*log2(e)

    // Per-lane fp32 weights for unit j (shared by both pair elements).
    float wx0[4][2], wh0[4][4], wx1[4][4], wh1[4][4];
    f2 b0v[4], b1v[4];
#pragma unroll
    for (int G = 0; G < 4; ++G){
        const float s = (G == 2) ? S2 : S1;
        const int r = G*4 + j;
        wx0[G][0] = Wih0[r*2+0]*s;
        wx0[G][1] = Wih0[r*2+1]*s;
#pragma unroll
        for (int k = 0; k < 4; ++k){
            wh0[G][k] = Whh0[r*4+k]*s;
            wx1[G][k] = Wih1[r*4+k]*s;
            wh1[G][k] = Whh1[r*4+k]*s;
        }
        b0v[G] = splat((bih0[r] + bhh0[r])*s);
        b1v[G] = splat((bih1[r] + bhh1[r])*s);
    }

    f2 c0 = splat(0.f), c1 = splat(0.f), acc = splat(0.f);
    f2 h0all[4], h1all[4];
#pragma unroll
    for (int k = 0; k < 4; ++k){ h0all[k] = splat(0.f); h1all[k] = splat(0.f); }

    const float* xp0 = x + (size_t)e0 * (T_LEN*I_IN);
    const float* xp1 = xp0 + (T_LEN*I_IN);

    // one packed step: both elements advance together on pk_fma
    auto step = [&](f2 x0, f2 x1, float wo){
        f2 g[4];
#pragma unroll
        for (int G = 0; G < 4; ++G){
            f2 a = pkfma_s(wx0[G][0], x0, b0v[G]);
            a = pkfma_s(wx0[G][1], x1, a);
#pragma unroll
            for (int k = 0; k < 4; ++k) a = pkfma_s(wh0[G][k], h0all[k], a);
            g[G] = a;
        }
        f2 h0;
        lstm_act2(g, c0, h0);
        h0all[0] = qdpp2<0x00>(h0); h0all[1] = qdpp2<0x55>(h0);
        h0all[2] = qdpp2<0xAA>(h0); h0all[3] = qdpp2<0xFF>(h0);

#pragma unroll
        for (int G = 0; G < 4; ++G){
            f2 a = b1v[G];
#pragma unroll
            for (int k = 0; k < 4; ++k) a = pkfma_s(wx1[G][k], h0all[k], a);
#pragma unroll
            for (int k = 0; k < 4; ++k) a = pkfma_s(wh1[G][k], h1all[k], a);
            g[G] = a;
        }
        f2 h1;
        lstm_act2(g, c1, h1);
        h1all[0] = qdpp2<0x00>(h1); h1all[1] = qdpp2<0x55>(h1);
        h1all[2] = qdpp2<0xAA>(h1); h1all[3] = qdpp2<0xFF>(h1);

        acc = pkfma_s(wo, h1, acc);
    };

#pragma unroll 2
    for (int tt = 0; tt < T_LEN/2; ++tt){
        const float4 xa = *reinterpret_cast<const float4*>(xp0 + tt*4);
        const float4 xb = *reinterpret_cast<const float4*>(xp1 + tt*4);
        const float wo0 = wout_s[(2*tt)*4 + j];
        const float wo1 = wout_s[(2*tt+1)*4 + j];
        f2 x0, x1;
        x0.x = xa.x; x0.y = xb.x;  x1.x = xa.y; x1.y = xb.y;
        step(x0, x1, wo0);
        x0.x = xa.z; x0.y = xb.z;  x1.x = xa.w; x1.y = xb.w;
        step(x0, x1, wo1);
    }

    // quad reductions (both halves in parallel)
    acc += qdpp2<0xB1>(acc);
    acc += qdpp2<0x4E>(acc);

    if (j == 0){
        const float z0 = acc.x + bout[0];
        const float z1 = acc.y + bout[0];
        out[e0]   = RCP(1.0f + EXP2(z0 * S1));
        out[e0+1] = RCP(1.0f + EXP2(z1 * S1));
    }
}

extern "C" void kernel_launch(void* const* d_in, const int* in_sizes, int n_in,
                              void* d_out, int out_size, void* d_ws, size_t ws_size,
                              hipStream_t stream)
{
    const float* x    = (const float*)d_in[0];
    const float* Wih0 = (const float*)d_in[1];
    const float* Whh0 = (const float*)d_in[2];
    const float* bih0 = (const float*)d_in[3];
    const float* bhh0 = (const float*)d_in[4];
    const float* Wih1 = (const float*)d_in[5];
    const float* Whh1 = (const float*)d_in[6];
    const float* bih1 = (const float*)d_in[7];
    const float* bhh1 = (const float*)d_in[8];
    const float* Wout = (const float*)d_in[9];
    const float* bout = (const float*)d_in[10];
    float* out = (float*)d_out;

    const int B = in_sizes[0] / (T_LEN*I_IN);
    const int total = (B/2) * 4;          // 4 lanes per 2 elements
    const int threads = 256;
    const int blocks = (total + threads - 1) / threads;
    lstm_fused<<<blocks, threads, 0, stream>>>(x, Wih0, Whh0, bih0, bhh0,
                                               Wih1, Whh1, bih1, bhh1,
                                               Wout, bout, out, B);
}

// Round 11
// 138.865 us; speedup vs baseline: 1.3899x; 1.3899x over previous
//
#include <hip/hip_runtime.h>

#define T_LEN 50
#define I_IN 2
#define HID 4

typedef float f2 __attribute__((ext_vector_type(2)));

__device__ __forceinline__ float EXP2(float x){
#if __has_builtin(__builtin_amdgcn_exp2f)
    return __builtin_amdgcn_exp2f(x);
#else
    return exp2f(x);
#endif
}
__device__ __forceinline__ float RCP(float x){
#if __has_builtin(__builtin_amdgcn_rcpf)
    return __builtin_amdgcn_rcpf(x);
#else
    return 1.0f/x;
#endif
}

__device__ __forceinline__ f2 splat(float v){ f2 r; r.x = v; r.y = v; return r; }

// packed fp32 fma (v_pk_fma_f32 when the backend cooperates)
__device__ __forceinline__ f2 pkfma(f2 a, f2 b, f2 c){
#if __has_builtin(__builtin_elementwise_fma)
    return __builtin_elementwise_fma(a, b, c);
#else
    f2 r; r.x = fmaf(a.x,b.x,c.x); r.y = fmaf(a.y,b.y,c.y); return r;
#endif
}
__device__ __forceinline__ f2 pkfma_s(float w, f2 x, f2 c){ return pkfma(splat(w), x, c); }

// quad_perm DPP move. Broadcast lane K of quad: CTRL=K*0x55. Swap pairs: 0xB1.
template<int CTRL>
__device__ __forceinline__ int qdpp_i(int v){
#if __has_builtin(__builtin_amdgcn_mov_dpp)
    return __builtin_amdgcn_mov_dpp(v, CTRL, 0xF, 0xF, true);
#else
    int lane = threadIdx.x & 63;
    int sel = (CTRL >> (2*(lane & 3))) & 3;
    return __shfl(v, (lane & ~3) + sel, 64);
#endif
}
template<int CTRL>
__device__ __forceinline__ float qdpp(float v){
    return __int_as_float(qdpp_i<CTRL>(__float_as_int(v)));
}
template<int CTRL>
__device__ __forceinline__ f2 qdpp2(f2 v){
    f2 r; r.x = qdpp<CTRL>(v.x); r.y = qdpp<CTRL>(v.y); return r;
}

// Packed-pair LSTM pointwise stage (two independent batch elements per lane).
// Gate pre-activations pre-scaled: i,f,o by S1=-log2e; g by S2=-2log2e.
// c' = [c*B*C + (1-q)*A] * rcp(A*B*C)  with p,r,q = 2^{scaled gates}
// h  = (1-u)*rcp((1+s)(1+u)),  s=2^{S1*o}, u=2^{S2*c'}  (clamped, finite-safe)
// hw exp + hw rcp: r6/r8/r10 proved any multi-instruction replacement regresses.
__device__ __forceinline__ void lstm_act2(const f2 g[4], f2& c, f2& h){
    const float S2 = -2.8853900817779268f;
    f2 p, r, q, s;
    p.x = EXP2(g[0].x); p.y = EXP2(g[0].y);
    r.x = EXP2(g[1].x); r.y = EXP2(g[1].y);
    q.x = EXP2(g[2].x); q.y = EXP2(g[2].y);
    s.x = EXP2(g[3].x); s.y = EXP2(g[3].y);
    const f2 one = splat(1.0f);
    const f2 A  = one + r;
    const f2 BC = (one + p) * (one + q);
    const f2 num = pkfma(c, BC, (one - q) * A);
    const f2 den = A * BC;
    f2 rd; rd.x = RCP(den.x); rd.y = RCP(den.y);
    c = num * rd;
    f2 ua = c * splat(S2);
    ua.x = fminf(ua.x, 96.0f); ua.y = fminf(ua.y, 96.0f);
    f2 u; u.x = EXP2(ua.x); u.y = EXP2(ua.y);
    const f2 dh = (one + s) * (one + u);
    f2 rh; rh.x = RCP(dh.x); rh.y = RCP(dh.y);
    h = (one - u) * rh;
}

__global__ __launch_bounds__(256) void lstm_fused(
    const float* __restrict__ x,
    const float* __restrict__ Wih0, const float* __restrict__ Whh0,
    const float* __restrict__ bih0, const float* __restrict__ bhh0,
    const float* __restrict__ Wih1, const float* __restrict__ Whh1,
    const float* __restrict__ bih1, const float* __restrict__ bhh1,
    const float* __restrict__ Wout, const float* __restrict__ bout,
    float* __restrict__ out, int B)
{
    __shared__ float wout_s[T_LEN*HID];
    const int tid = threadIdx.x;
    if (tid < T_LEN*HID) wout_s[tid] = Wout[tid];
    __syncthreads();

    const int gtid = blockIdx.x*256 + tid;
    const int q2 = gtid >> 2;          // quad id, owns elements 2*q2, 2*q2+1
    const int j = tid & 3;             // hidden unit owned by this lane
    const int e0 = q2*2;
    if (e0 >= B) return;

    const float S1 = -1.4426950408889634f;   // -log2(e)
    const float S2 = -2.8853900817779268f;   // -2*log2(e)

    // Per-lane fp32 weights for unit j (shared by both pair elements).
    float wx0[4][2], wh0[4][4], wx1[4][4], wh1[4][4];
    f2 b0v[4], b1v[4];
#pragma unroll
    for (int G = 0; G < 4; ++G){
        const float s = (G == 2) ? S2 : S1;
        const int r = G*4 + j;
        wx0[G][0] = Wih0[r*2+0]*s;
        wx0[G][1] = Wih0[r*2+1]*s;
#pragma unroll
        for (int k = 0; k < 4; ++k){
            wh0[G][k] = Whh0[r*4+k]*s;
            wx1[G][k] = Wih1[r*4+k]*s;
            wh1[G][k] = Whh1[r*4+k]*s;
        }
        b0v[G] = splat((bih0[r] + bhh0[r])*s);
        b1v[G] = splat((bih1[r] + bhh1[r])*s);
    }

    f2 c0 = splat(0.f), c1 = splat(0.f), acc = splat(0.f);
    f2 h0all[4], h1all[4];
#pragma unroll
    for (int k = 0; k < 4; ++k){ h0all[k] = splat(0.f); h1all[k] = splat(0.f); }

    const float* xp0 = x + (size_t)e0 * (T_LEN*I_IN);
    const float* xp1 = xp0 + (T_LEN*I_IN);

    // one packed step: both elements advance together on pk_fma
    auto step = [&](f2 x0, f2 x1, float wo){
        f2 g[4];
#pragma unroll
        for (int G = 0; G < 4; ++G){
            f2 a = pkfma_s(wx0[G][0], x0, b0v[G]);
            a = pkfma_s(wx0[G][1], x1, a);
#pragma unroll
            for (int k = 0; k < 4; ++k) a = pkfma_s(wh0[G][k], h0all[k], a);
            g[G] = a;
        }
        f2 h0;
        lstm_act2(g, c0, h0);
        h0all[0] = qdpp2<0x00>(h0); h0all[1] = qdpp2<0x55>(h0);
        h0all[2] = qdpp2<0xAA>(h0); h0all[3] = qdpp2<0xFF>(h0);

#pragma unroll
        for (int G = 0; G < 4; ++G){
            f2 a = b1v[G];
#pragma unroll
            for (int k = 0; k < 4; ++k) a = pkfma_s(wx1[G][k], h0all[k], a);
#pragma unroll
            for (int k = 0; k < 4; ++k) a = pkfma_s(wh1[G][k], h1all[k], a);
            g[G] = a;
        }
        f2 h1;
        lstm_act2(g, c1, h1);
        h1all[0] = qdpp2<0x00>(h1); h1all[1] = qdpp2<0x55>(h1);
        h1all[2] = qdpp2<0xAA>(h1); h1all[3] = qdpp2<0xFF>(h1);

        acc = pkfma_s(wo, h1, acc);
    };

    // software-pipelined x: prefetch next iteration's float4s before computing,
    // so the HBM/L3 latency hides under ~2 pair-steps of compute.
    float4 xa = *reinterpret_cast<const float4*>(xp0);
    float4 xb = *reinterpret_cast<const float4*>(xp1);
#pragma unroll 5
    for (int tt = 0; tt < T_LEN/2; ++tt){
        const int ttn = (tt + 1 < T_LEN/2) ? (tt + 1) : tt;   // clamped, in-bounds
        const float4 xa_n = *reinterpret_cast<const float4*>(xp0 + ttn*4);
        const float4 xb_n = *reinterpret_cast<const float4*>(xp1 + ttn*4);

        const float wo0 = wout_s[(2*tt)*4 + j];
        const float wo1 = wout_s[(2*tt+1)*4 + j];
        f2 x0, x1;
        x0.x = xa.x; x0.y = xb.x;  x1.x = xa.y; x1.y = xb.y;
        step(x0, x1, wo0);
        x0.x = xa.z; x0.y = xb.z;  x1.x = xa.w; x1.y = xb.w;
        step(x0, x1, wo1);

        xa = xa_n; xb = xb_n;
    }

    // quad reductions (both halves in parallel)
    acc += qdpp2<0xB1>(acc);
    acc += qdpp2<0x4E>(acc);

    if (j == 0){
        const float z0 = acc.x + bout[0];
        const float z1 = acc.y + bout[0];
        out[e0]   = RCP(1.0f + EXP2(z0 * S1));
        out[e0+1] = RCP(1.0f + EXP2(z1 * S1));
    }
}

extern "C" void kernel_launch(void* const* d_in, const int* in_sizes, int n_in,
                              void* d_out, int out_size, void* d_ws, size_t ws_size,
                              hipStream_t stream)
{
    const float* x    = (const float*)d_in[0];
    const float* Wih0 = (const float*)d_in[1];
    const float* Whh0 = (const float*)d_in[2];
    const float* bih0 = (const float*)d_in[3];
    const float* bhh0 = (const float*)d_in[4];
    const float* Wih1 = (const float*)d_in[5];
    const float* Whh1 = (const float*)d_in[6];
    const float* bih1 = (const float*)d_in[7];
    const float* bhh1 = (const float*)d_in[8];
    const float* Wout = (const float*)d_in[9];
    const float* bout = (const float*)d_in[10];
    float* out = (float*)d_out;

    const int B = in_sizes[0] / (T_LEN*I_IN);
    const int total = (B/2) * 4;          // 4 lanes per 2 elements
    const int threads = 256;
    const int blocks = (total + threads - 1) / threads;
    lstm_fused<<<blocks, threads, 0, stream>>>(x, Wih0, Whh0, bih0, bhh0,
                                               Wih1, Whh1, bih1, bhh1,
                                               Wout, bout, out, B);
}

// Round 12
// 109.203 us; speedup vs baseline: 1.7674x; 1.2716x over previous
//
#include <hip/hip_runtime.h>

#define T_LEN 50
#define I_IN 2

typedef __fp16 fp16x8 __attribute__((ext_vector_type(8)));
typedef float f32x4 __attribute__((ext_vector_type(4)));
typedef unsigned int uint4v __attribute__((ext_vector_type(4)));

__device__ __forceinline__ float EXP2(float x){ return __builtin_amdgcn_exp2f(x); }
__device__ __forceinline__ float RCP(float x){ return __builtin_amdgcn_rcpf(x); }
// pack two f32 -> two f16 in one u32 (v_cvt_pkrtz_f16_f32)
__device__ __forceinline__ unsigned PKU(float a, float b){
    return __builtin_bit_cast(unsigned, __builtin_amdgcn_cvt_pkrtz(a, b));
}

// LSTM pointwise stage, one (unit, element) per lane.
// Gate pre-acts arrive pre-scaled (weights/bias folded): i,f,o by -log2e; g by -2log2e.
// c' = [c*B*C + (1-q)*A] * rcp(A*B*C); h = (1-u)*rcp((1+s)(1+u)), u=2^min(c*S2,96)
__device__ __forceinline__ void act(const f32x4 gt, float& c, float& h){
    const float S2 = -2.8853900817779268f;
    const float p = EXP2(gt[0]);          // i
    const float r = EXP2(gt[1]);          // f
    const float q = EXP2(gt[2]);          // g
    const float s = EXP2(gt[3]);          // o
    const float A  = 1.0f + r;
    const float BC = (1.0f + p) * (1.0f + q);
    const float num = fmaf(c, BC, (1.0f - q) * A);
    c = num * RCP(A * BC);
    const float u = EXP2(fminf(c * S2, 96.0f));
    h = (1.0f - u) * RCP((1.0f + s) * (1.0f + u));
}

// Wave layout: 16 elements/wave. lane = 16*g + e.
//   D/C of mfma_16x16x32 (verified m89): col = lane&15 = e, row = 4*g + reg.
//   A rows permuted m = 4j+t  <->  PyTorch W row r = t*4+j  => lane(g,e) gets
//   gate-type t=reg of unit j=g for element e. Activation is lane-local.
//   A-operand: lane supplies A[m=lane&15][k=8g+i]; B: B[k=8g+i][n=lane&15].
//   K usage: L0: k={x0,x1,h0[0..3]}, L1: k={h0[0..3], h1[0..3]}; rest zero.
__global__ __launch_bounds__(256, 8) void lstm_mfma(
    const float* __restrict__ x,
    const float* __restrict__ Wih0, const float* __restrict__ Whh0,
    const float* __restrict__ bih0, const float* __restrict__ bhh0,
    const float* __restrict__ Wih1, const float* __restrict__ Whh1,
    const float* __restrict__ bih1, const float* __restrict__ bhh1,
    const float* __restrict__ Wout, const float* __restrict__ bout,
    float* __restrict__ out, int B)
{
    __shared__ float wout_s[T_LEN*4];
    const int tid = threadIdx.x;
    if (tid < T_LEN*4) wout_s[tid] = Wout[tid];
    __syncthreads();

    const int lane = tid & 63;
    const int e = lane & 15;          // element within wave tile
    const int g = lane >> 4;          // lane group = hidden unit for D/C
    const bool g0 = (g == 0);
    const int wave = (blockIdx.x * 256 + tid) >> 6;
    const int E0 = wave * 16;
    if (E0 >= B) return;

    const float S1 = -1.4426950408889634f;   // -log2(e)
    const float S2 = -2.8853900817779268f;   // -2*log2(e)

    // ---- A fragments (weights, f16). Lane supplies row m=e, k=8g+i. ----
    const int ja = e >> 2, ta = e & 3;
    const int ra = ta*4 + ja;                 // original W row (PyTorch order)
    const float sa = (ta == 2) ? S2 : S1;

    uint4v a0u, a1u;
#pragma unroll
    for (int p_ = 0; p_ < 4; ++p_){
        float v[2][2]; // [which half][layer]
#pragma unroll
        for (int h_ = 0; h_ < 2; ++h_){
            const int k = 8*g + 2*p_ + h_;
            float v0 = 0.f, v1 = 0.f;
            if (k < 2)      v0 = Wih0[ra*2 + k] * sa;
            else if (k < 6) v0 = Whh0[ra*4 + (k-2)] * sa;
            if (k < 4)      v1 = Wih1[ra*4 + k] * sa;
            else if (k < 8) v1 = Whh1[ra*4 + (k-4)] * sa;
            v[h_][0] = v0; v[h_][1] = v1;
        }
        a0u[p_] = PKU(v[0][0], v[1][0]);
        a1u[p_] = PKU(v[0][1], v[1][1]);
    }
    const fp16x8 A0 = __builtin_bit_cast(fp16x8, a0u);
    const fp16x8 A1 = __builtin_bit_cast(fp16x8, a1u);

    // ---- bias as MFMA C operand: lane(g,e) holds rows m=4g+t, t=0..3 ----
    f32x4 bias0, bias1;
#pragma unroll
    for (int t = 0; t < 4; ++t){
        const int r = t*4 + g;
        const float st = (t == 2) ? S2 : S1;
        bias0[t] = (bih0[r] + bhh0[r]) * st;
        bias1[t] = (bih1[r] + bhh1[r]) * st;
    }

    float c0 = 0.f, c1 = 0.f, acc = 0.f;
    unsigned hp0 = 0u, hp1 = 0u;   // packed h0 (units 0,1 | 2,3), masked to group 0
    unsigned hr0 = 0u, hr1 = 0u;   // packed h1 likewise

    const float* xp = x + (size_t)(E0 + e) * (T_LEN*I_IN);

    for (int tt = 0; tt < T_LEN/2; ++tt){
        const float4 xv = *reinterpret_cast<const float4*>(xp + tt*4);
#pragma unroll
        for (int hh = 0; hh < 2; ++hh){
            const float x0 = hh ? xv.z : xv.x;
            const float x1 = hh ? xv.w : xv.y;
            const unsigned ux = g0 ? PKU(x0, x1) : 0u;

            // ---- layer 0: gates = A0 @ [x;h0] + bias ----
            uint4v b0u; b0u[0] = ux; b0u[1] = hp0; b0u[2] = hp1; b0u[3] = 0u;
            const f32x4 gt0 = __builtin_amdgcn_mfma_f32_16x16x32_f16(
                A0, __builtin_bit_cast(fp16x8, b0u), bias0, 0, 0, 0);
            float h0;
            act(gt0, c0, h0);

            // gather h0 units 0..3 of my element, pack for B (group0 only)
            {
                const float p0 = __shfl(h0, e,      64);
                const float p1 = __shfl(h0, e + 16, 64);
                const float p2 = __shfl(h0, e + 32, 64);
                const float p3 = __shfl(h0, e + 48, 64);
                hp0 = g0 ? PKU(p0, p1) : 0u;
                hp1 = g0 ? PKU(p2, p3) : 0u;
            }

            // ---- layer 1: gates = A1 @ [h0;h1] + bias ----
            uint4v b1u; b1u[0] = hp0; b1u[1] = hp1; b1u[2] = hr0; b1u[3] = hr1;
            const f32x4 gt1 = __builtin_amdgcn_mfma_f32_16x16x32_f16(
                A1, __builtin_bit_cast(fp16x8, b1u), bias1, 0, 0, 0);
            float h1;
            act(gt1, c1, h1);

            {
                const float q0 = __shfl(h1, e,      64);
                const float q1 = __shfl(h1, e + 16, 64);
                const float q2 = __shfl(h1, e + 32, 64);
                const float q3 = __shfl(h1, e + 48, 64);
                hr0 = g0 ? PKU(q0, q1) : 0u;
                hr1 = g0 ? PKU(q2, q3) : 0u;
            }

            // output projection: lane(g,e): h1 is (unit g, elem e)
            acc = fmaf(h1, wout_s[(2*tt + hh)*4 + g], acc);
        }
    }

    // sum over the 4 unit-groups for each element
    acc += __shfl_xor(acc, 16, 64);
    acc += __shfl_xor(acc, 32, 64);

    if (lane < 16){
        const float z = acc + bout[0];
        out[E0 + e] = RCP(1.0f + EXP2(z * S1));   // sigmoid
    }
}

extern "C" void kernel_launch(void* const* d_in, const int* in_sizes, int n_in,
                              void* d_out, int out_size, void* d_ws, size_t ws_size,
                              hipStream_t stream)
{
    const float* x    = (const float*)d_in[0];
    const float* Wih0 = (const float*)d_in[1];
    const float* Whh0 = (const float*)d_in[2];
    const float* bih0 = (const float*)d_in[3];
    const float* bhh0 = (const float*)d_in[4];
    const float* Wih1 = (const float*)d_in[5];
    const float* Whh1 = (const float*)d_in[6];
    const float* bih1 = (const float*)d_in[7];
    const float* bhh1 = (const float*)d_in[8];
    const float* Wout = (const float*)d_in[9];
    const float* bout = (const float*)d_in[10];
    float* out = (float*)d_out;

    const int B = in_sizes[0] / (T_LEN*I_IN);
    const int waves = (B + 15) / 16;
    const int blocks = (waves + 3) / 4;       // 4 waves (256 threads) per block
    lstm_mfma<<<blocks, 256, 0, stream>>>(x, Wih0, Whh0, bih0, bhh0,
                                          Wih1, Whh1, bih1, bhh1,
                                          Wout, bout, out, B);
}